// Round 1
// baseline (232.378 us; speedup 1.0000x reference)
//
#include <hip/hip_runtime.h>
#include <cstdint>

#define NB   4
#define CIN  64
#define HH   256
#define WW   256
#define COUT 128
#define NP   4096   // Hp*Wp
#define KDIM 1024   // CIN*16
#define OD   128    // Cout / head dim

typedef _Float16 h16;
typedef _Float16 h16x8 __attribute__((ext_vector_type(8)));
typedef _Float16 h16x4 __attribute__((ext_vector_type(4)));
typedef _Float16 h16x2 __attribute__((ext_vector_type(2)));
typedef float    f32x4 __attribute__((ext_vector_type(4)));

// ---------------------------------------------------------------------------
// Conv-as-GEMM: per (b, ph, mat): D[128 o x 64 n] = W[128x1024] * P[1024x64]
// P[k=(c,kh,kw)][n=pw] = x[b, c, 4*ph+kh, 4*pw+kw]  (stride==kernel patches)
// Outputs fp16: qt/kt as [b][n][o] (transposed), vt as [b][o][n].
// ---------------------------------------------------------------------------
__global__ __launch_bounds__(256) void conv_qkv(
    const float* __restrict__ x,
    const float* __restrict__ Wq, const float* __restrict__ bq,
    const float* __restrict__ Wk, const float* __restrict__ bk,
    const float* __restrict__ Wv, const float* __restrict__ bv,
    h16* __restrict__ qt, h16* __restrict__ kt, h16* __restrict__ vt)
{
    const int mat = blockIdx.y;
    const float* Wm = (mat == 0) ? Wq : (mat == 1) ? Wk : Wv;
    const float* bm = (mat == 0) ? bq : (mat == 1) ? bk : bv;
    const int ph  = blockIdx.x;          // n-tile == one ph row (64 pw)
    const int b   = blockIdx.z;
    const int tid = threadIdx.x;
    const int lane = tid & 63, wv = tid >> 6;
    const int lr = lane & 15, qd = lane >> 4;
    const int o_w = 64 * (wv >> 1);      // wave o-offset (2x2 wave grid)
    const int n_w = 32 * (wv & 1);       // wave n-offset

    __shared__ __align__(16) char smem[17152];
    h16*   Wl    = (h16*)smem;               // [128][40] fp16 (32k + pad8)
    h16*   Pl    = (h16*)(smem + 10240);     // [64][40]  fp16
    float* biasl = (float*)(smem + 16640);   // [128]
    h16*   bnc   = (h16*)smem;               // [64][130] fp16 epilogue bounce (alias)

    if (tid < 128) biasl[tid] = bm[tid];

    f32x4 acc[4][2];
#pragma unroll
    for (int a = 0; a < 4; ++a)
#pragma unroll
        for (int c = 0; c < 2; ++c) acc[a][c] = (f32x4){0.f, 0.f, 0.f, 0.f};

    for (int kc = 0; kc < 32; ++kc) {   // K-chunks of 32 (= 2 input channels)
        // stage W chunk [128 o][32 k] fp32 -> fp16 LDS
#pragma unroll
        for (int j = 0; j < 4; ++j) {
            int i = tid + 256 * j;
            int o = i >> 3, k4 = i & 7;
            f32x4 w4 = *(const f32x4*)(Wm + (size_t)o * KDIM + kc * 32 + 4 * k4);
            h16x4 h4 = {(h16)w4.x, (h16)w4.y, (h16)w4.z, (h16)w4.w};
            *(h16x4*)&Wl[o * 40 + 4 * k4] = h4;
        }
        // stage patch chunk [64 n][32 k]: float4 = 4 kw at fixed (c,kh,pw)
#pragma unroll
        for (int j = 0; j < 2; ++j) {
            int i  = tid + 256 * j;
            int pw = i & 63, kh = (i >> 6) & 3, c = (i >> 8) & 1;
            const float* px = x + (((size_t)(b * CIN + kc * 2 + c) * HH) + 4 * ph + kh) * WW + 4 * pw;
            f32x4 x4 = *(const f32x4*)px;
            h16x4 h4 = {(h16)x4.x, (h16)x4.y, (h16)x4.z, (h16)x4.w};
            *(h16x4*)&Pl[pw * 40 + c * 16 + kh * 4] = h4;
        }
        __syncthreads();

        h16x8 af[4], bf[2];
#pragma unroll
        for (int to = 0; to < 4; ++to)
            af[to] = *(const h16x8*)&Wl[(o_w + 16 * to + lr) * 40 + 8 * qd];
#pragma unroll
        for (int tn = 0; tn < 2; ++tn)
            bf[tn] = *(const h16x8*)&Pl[(n_w + 16 * tn + lr) * 40 + 8 * qd];
#pragma unroll
        for (int to = 0; to < 4; ++to)
#pragma unroll
            for (int tn = 0; tn < 2; ++tn)
                acc[to][tn] = __builtin_amdgcn_mfma_f32_16x16x32_f16(af[to], bf[tn], acc[to][tn], 0, 0, 0);
        __syncthreads();
    }

    // epilogue: bias + bounce to LDS [n][o] (D-layout: row=o=4*qd+r, col=n=lr)
#pragma unroll
    for (int to = 0; to < 4; ++to)
#pragma unroll
        for (int tn = 0; tn < 2; ++tn)
#pragma unroll
            for (int r = 0; r < 4; ++r) {
                int o_l = o_w + 16 * to + 4 * qd + r;
                int n_l = n_w + 16 * tn + lr;
                bnc[n_l * 130 + o_l] = (h16)(acc[to][tn][r] + biasl[o_l]);
            }
    __syncthreads();

    const int n0 = ph * 64;
    if (mat < 2) {
        h16* dst = (mat == 0) ? qt : kt;   // [b][n][o]
#pragma unroll
        for (int j = 0; j < 16; ++j) {
            int i = tid + 256 * j;
            int n = i >> 6, o2 = i & 63;
            h16x2 hh = {bnc[n * 130 + 2 * o2], bnc[n * 130 + 2 * o2 + 1]};
            *(h16x2*)(dst + ((size_t)(b * NP + n0 + n)) * OD + 2 * o2) = hh;
        }
    } else {                               // [b][o][n]
#pragma unroll
        for (int j = 0; j < 16; ++j) {
            int i = tid + 256 * j;
            int o = i >> 5, n2 = i & 31;
            h16x2 hh = {bnc[(2 * n2) * 130 + o], bnc[(2 * n2 + 1) * 130 + o]};
            *(h16x2*)(vt + ((size_t)(b * OD + o)) * NP + n0 + 2 * n2) = hh;
        }
    }
}

// ---------------------------------------------------------------------------
// Flash attention: BQ=64 rows/block (wave owns 16 rows), BM=64 K/V tiles,
// register-prefetch double staging, Q-fragments register-resident.
// out[b][o][n] = sum_m softmax_m(Q^T K)[n,m] * v[o,m]
// ---------------------------------------------------------------------------
__global__ __launch_bounds__(256) void flash_attn(
    const h16* __restrict__ qt, const h16* __restrict__ kt,
    const h16* __restrict__ vt, float* __restrict__ out)
{
    const int nt = blockIdx.x, b = blockIdx.y;
    const int n0 = nt * 64;
    const int tid = threadIdx.x;
    const int lane = tid & 63, wv = tid >> 6;
    const int lr = lane & 15, qd = lane >> 4;

    __shared__ __align__(16) char smem[45056];
    h16*   Kl  = (h16*)smem;              // [64 m][136] (128 o + pad8)
    h16*   Vl  = (h16*)(smem + 17408);    // [128 o][72] (64 m + pad8)
    h16*   Pl  = (h16*)(smem + 35840);    // 4 waves x [16 n][72]
    float* bnc = (float*)smem;            // [64 n][129] fp32 (alias K+V)

    // Q fragments, register-resident for whole m-loop: A[row n=lr][k o=32kc+8qd+j]
    h16x8 qf[4];
    const h16* qrow = qt + ((size_t)(b * NP + n0 + 16 * wv + lr)) * OD;
#pragma unroll
    for (int kc = 0; kc < 4; ++kc) qf[kc] = *(const h16x8*)(qrow + 32 * kc + 8 * qd);

    float m_run[4], l_run[4];
#pragma unroll
    for (int r = 0; r < 4; ++r) { m_run[r] = -1e30f; l_run[r] = 0.f; }
    f32x4 oacc[8];
#pragma unroll
    for (int t = 0; t < 8; ++t) oacc[t] = (f32x4){0.f, 0.f, 0.f, 0.f};

    h16x8 kreg[4], vreg[4];
    auto loadt = [&](int it) {
        int m0 = 64 * it;
#pragma unroll
        for (int j = 0; j < 4; ++j) {
            int i = tid + 256 * j;
            kreg[j] = *(const h16x8*)(kt + ((size_t)(b * NP + m0 + (i >> 4))) * OD + 8 * (i & 15));
            vreg[j] = *(const h16x8*)(vt + ((size_t)(b * OD + (i >> 3))) * NP + m0 + 8 * (i & 7));
        }
    };
    auto writet = [&]() {
#pragma unroll
        for (int j = 0; j < 4; ++j) {
            int i = tid + 256 * j;
            *(h16x8*)&Kl[(i >> 4) * 136 + 8 * (i & 15)] = kreg[j];
            *(h16x8*)&Vl[(i >> 3) * 72 + 8 * (i & 7)]   = vreg[j];
        }
    };

    loadt(0);
    writet();
    __syncthreads();

    h16* Plw = Pl + wv * (16 * 72);

    for (int it = 0; it < 64; ++it) {
        if (it + 1 < 64) loadt(it + 1);   // prefetch into regs, in flight

        // S[t][r]: row n = 4*qd + r (wave-local), col m = 16*t + lr
        f32x4 s[4];
#pragma unroll
        for (int t = 0; t < 4; ++t) {
            s[t] = (f32x4){0.f, 0.f, 0.f, 0.f};
#pragma unroll
            for (int kc = 0; kc < 4; ++kc) {
                h16x8 bf = *(const h16x8*)&Kl[(16 * t + lr) * 136 + 32 * kc + 8 * qd];
                s[t] = __builtin_amdgcn_mfma_f32_16x16x32_f16(qf[kc], bf, s[t], 0, 0, 0);
            }
        }

        // online softmax (fp32): row reduce across the 16 lanes of each quad
        float mx[4], al[4], rs[4], p[4][4];
#pragma unroll
        for (int r = 0; r < 4; ++r)
            mx[r] = fmaxf(fmaxf(s[0][r], s[1][r]), fmaxf(s[2][r], s[3][r]));
#pragma unroll
        for (int d = 1; d < 16; d <<= 1)
#pragma unroll
            for (int r = 0; r < 4; ++r)
                mx[r] = fmaxf(mx[r], __shfl_xor(mx[r], d, 64));
#pragma unroll
        for (int r = 0; r < 4; ++r) {
            float mn = fmaxf(m_run[r], mx[r]);
            al[r] = __expf(m_run[r] - mn);
            m_run[r] = mn;
        }
#pragma unroll
        for (int t = 0; t < 4; ++t)
#pragma unroll
            for (int r = 0; r < 4; ++r)
                p[t][r] = __expf(s[t][r] - m_run[r]);
#pragma unroll
        for (int r = 0; r < 4; ++r)
            rs[r] = (p[0][r] + p[1][r]) + (p[2][r] + p[3][r]);
#pragma unroll
        for (int d = 1; d < 16; d <<= 1)
#pragma unroll
            for (int r = 0; r < 4; ++r)
                rs[r] += __shfl_xor(rs[r], d, 64);
#pragma unroll
        for (int r = 0; r < 4; ++r)
            l_run[r] = l_run[r] * al[r] + rs[r];
#pragma unroll
        for (int to = 0; to < 8; ++to)
#pragma unroll
            for (int r = 0; r < 4; ++r)
                oacc[to][r] *= al[r];

        // P: D-layout -> LDS [n][m] -> A-layout (wave-private, no barrier)
#pragma unroll
        for (int t = 0; t < 4; ++t)
#pragma unroll
            for (int r = 0; r < 4; ++r)
                Plw[(4 * qd + r) * 72 + 16 * t + lr] = (h16)p[t][r];

        h16x8 pf[2];
#pragma unroll
        for (int kc = 0; kc < 2; ++kc)
            pf[kc] = *(const h16x8*)&Plw[lr * 72 + 32 * kc + 8 * qd];
#pragma unroll
        for (int to = 0; to < 8; ++to)
#pragma unroll
            for (int kc = 0; kc < 2; ++kc) {
                h16x8 bvf = *(const h16x8*)&Vl[(16 * to + lr) * 72 + 32 * kc + 8 * qd];
                oacc[to] = __builtin_amdgcn_mfma_f32_16x16x32_f16(pf[kc], bvf, oacc[to], 0, 0, 0);
            }

        __syncthreads();                 // everyone done reading Kl/Vl
        if (it + 1 < 64) writet();       // regs -> LDS for next tile
        __syncthreads();
    }

    // normalize and store via LDS bounce for coalesced fp32 stores
#pragma unroll
    for (int r = 0; r < 4; ++r) l_run[r] = 1.f / l_run[r];
#pragma unroll
    for (int to = 0; to < 8; ++to)
#pragma unroll
        for (int r = 0; r < 4; ++r)
            bnc[(16 * wv + 4 * qd + r) * 129 + 16 * to + lr] = oacc[to][r] * l_run[r];
    __syncthreads();

    float* ob = out + (size_t)b * OD * NP;
#pragma unroll
    for (int j = 0; j < 32; ++j) {
        int i = tid + 256 * j;
        int o = i >> 6, nn = i & 63;
        ob[(size_t)o * NP + n0 + nn] = bnc[nn * 129 + o];
    }
}

extern "C" void kernel_launch(void* const* d_in, const int* in_sizes, int n_in,
                              void* d_out, int out_size, void* d_ws, size_t ws_size,
                              hipStream_t stream) {
    const float* x  = (const float*)d_in[0];
    const float* Wq = (const float*)d_in[1];
    const float* bq = (const float*)d_in[2];
    const float* Wk = (const float*)d_in[3];
    const float* bk = (const float*)d_in[4];
    const float* Wv = (const float*)d_in[5];
    const float* bv = (const float*)d_in[6];

    h16* qtp = (h16*)d_ws;                        // [B][N][O] fp16, 4 MB
    h16* ktp = qtp + (size_t)NB * NP * OD;        // [B][N][O] fp16, 4 MB
    h16* vtp = ktp + (size_t)NB * NP * OD;        // [B][O][N] fp16, 4 MB
    float* out = (float*)d_out;

    conv_qkv<<<dim3(64, 3, NB), 256, 0, stream>>>(x, Wq, bq, Wk, bk, Wv, bv, qtp, ktp, vtp);
    flash_attn<<<dim3(NP / 64, NB), 256, 0, stream>>>(qtp, ktp, vtp, out);
}